// Round 11
// baseline (216.230 us; speedup 1.0000x reference)
//
#include <hip/hip_runtime.h>
#include <hip/hip_bf16.h>

// Problem constants: B=2, T=4096, C=768, H=12, D=64
#define T_SEQ 4096
#define C_DIM 768
#define H_NUM 12
#define D_HEAD 64
#define N3    2304   // 3*C
#define BHN   24     // B*H

typedef __bf16 bf16x8 __attribute__((ext_vector_type(8)));
typedef float  f32x4  __attribute__((ext_vector_type(4)));
typedef unsigned int u32x4v __attribute__((ext_vector_type(4)));

// fp32 -> bf16 (round-to-nearest-even), raw bits
__device__ inline unsigned short f2b(float f) {
    unsigned int x = __float_as_uint(f);
    unsigned int r = (x + 0x7FFFu + ((x >> 16) & 1u)) >> 16;
    return (unsigned short)r;
}

__device__ inline float b2f(unsigned short u) {
    return __uint_as_float(((unsigned int)u) << 16);
}

// pack two f32 -> two bf16 (TRUNCATED) in one v_perm_b32: low half = lo
__device__ inline unsigned int pack_trunc(float lo, float hi) {
    return __builtin_amdgcn_perm(__float_as_uint(hi), __float_as_uint(lo), 0x07060302u);
}

// 16B-per-lane async global->LDS (dest = wave-uniform base + lane*16)
__device__ inline void load_lds16(const unsigned short* g, unsigned short* l) {
    __builtin_amdgcn_global_load_lds(
        (const __attribute__((address_space(1))) unsigned int*)(g),
        (__attribute__((address_space(3))) unsigned int*)(l),
        16, 0, 0);
}

// ---------------------------------------------------------------------------
// prep: fused [convert x -> bf16] + [transpose qkv_w] + [transpose out_w]
// ---------------------------------------------------------------------------
__device__ inline void transpose_tile(const float* __restrict__ in,
                                      unsigned short* __restrict__ out,
                                      unsigned short* Ts, int k0, int n0,
                                      int R, int Cc, int tid)
{
    #pragma unroll
    for (int it = 0; it < 4; ++it) {
        int idx = tid + it * 256;
        int r = idx >> 4, c4 = idx & 15;
        float4 v = *reinterpret_cast<const float4*>(&in[(size_t)(k0 + r) * Cc + n0 + c4 * 4]);
        Ts[(c4 * 4 + 0) * 72 + r] = f2b(v.x);
        Ts[(c4 * 4 + 1) * 72 + r] = f2b(v.y);
        Ts[(c4 * 4 + 2) * 72 + r] = f2b(v.z);
        Ts[(c4 * 4 + 3) * 72 + r] = f2b(v.w);
    }
    __syncthreads();
    #pragma unroll
    for (int it = 0; it < 2; ++it) {
        int idx = tid + it * 256;
        int row = idx >> 3, ch = idx & 7;
        *reinterpret_cast<uint4*>(&out[(size_t)(n0 + row) * R + k0 + ch * 8]) =
            *reinterpret_cast<const uint4*>(&Ts[row * 72 + ch * 8]);
    }
}

__global__ __launch_bounds__(256) void prep(
    const float* __restrict__ x, const float* __restrict__ qkv_w,
    const float* __restrict__ out_w,
    unsigned short* __restrict__ xb, unsigned short* __restrict__ wtq,
    unsigned short* __restrict__ wto)
{
    __shared__ unsigned short Ts[64 * 72];
    const int b = blockIdx.x, tid = threadIdx.x;
    if (b < 6144) {
        int idx = b * 256 + tid;
        float4 v = reinterpret_cast<const float4*>(x)[idx];
        ushort4 u;
        u.x = f2b(v.x); u.y = f2b(v.y); u.z = f2b(v.z); u.w = f2b(v.w);
        reinterpret_cast<ushort4*>(xb)[idx] = u;
    } else if (b < 6576) {
        int bb = b - 6144;
        transpose_tile(qkv_w, wtq, Ts, (bb % 12) * 64, (bb / 12) * 64, C_DIM, N3, tid);
    } else {
        int bb = b - 6576;
        transpose_tile(out_w, wto, Ts, (bb % 12) * 64, (bb / 12) * 64, C_DIM, C_DIM, tid);
    }
}

// ---------------------------------------------------------------------------
// QKV projection, R16: 128x128 tile (m97 structure) + __launch_bounds__(256,3)
// (R14, verified) + bijective XCD swizzle (1152 = 8 x 144: each XCD owns a
// contiguous 144-block range = ~2.25 B-panels -> panel reads are XCD-L2-local
// instead of replicated across all 8 L2s).
// V written sigma-PERMUTED along T within each 64-key tile:
//   sigma(k) = (k&32) + ((k>>2)&3)*8 + ((k>>4)&1)*4 + (k&3)
// so flash's PV B-operand is the QK output registers verbatim.
// ---------------------------------------------------------------------------
__global__ __launch_bounds__(256, 3) void qkv_gemm(
    const unsigned short* __restrict__ xb, const unsigned short* __restrict__ wt,
    const float* __restrict__ bias,
    unsigned short* __restrict__ Q, unsigned short* __restrict__ K,
    unsigned short* __restrict__ Vt)
{
    __shared__ unsigned short SH[128 * 128];   // As | Bs ; reused as Ct in V epilogue
    unsigned short* As = SH;                   // [128][64] xor-swizzled chunks
    unsigned short* Bs = SH + 128 * 64;        // [128][64]
    const int tid  = threadIdx.x;
    const int bid  = blockIdx.y * 64 + blockIdx.x;
    const int swz  = (bid & 7) * 144 + (bid >> 3);   // XCD-contiguous (1152 = 8*144)
    const int m0   = (swz & 63) * 128;
    const int n0   = (swz >> 6) * 128;
    const int lane = tid & 63;
    const int wv   = tid >> 6;
    const int wr   = wv >> 1, wc = wv & 1;
    const int quad = lane >> 4;
    const int lr   = lane & 15;
    const int srow = lane >> 3;
    const int dch  = (lane & 7) ^ srow;

    f32x4 acc[4][4] = {};

    for (int kk = 0; kk < C_DIM; kk += 64) {
        __syncthreads();
        #pragma unroll
        for (int i = 0; i < 4; ++i) {
            int inst = wv * 4 + i;
            int r = inst * 8 + srow;
            load_lds16(xb + (size_t)(m0 + r) * C_DIM + kk + dch * 8, As + inst * 512);
            load_lds16(wt + (size_t)(n0 + r) * C_DIM + kk + dch * 8, Bs + inst * 512);
        }
        __syncthreads();
        #pragma unroll
        for (int k2 = 0; k2 < 2; ++k2) {
            bf16x8 af[4], bf[4];
            #pragma unroll
            for (int mt = 0; mt < 4; ++mt)
                af[mt] = *reinterpret_cast<const bf16x8*>(
                    &As[(wr * 64 + mt * 16 + lr) * 64 + (((k2 * 4 + quad) ^ (lr & 7)) * 8)]);
            #pragma unroll
            for (int nt = 0; nt < 4; ++nt)
                bf[nt] = *reinterpret_cast<const bf16x8*>(
                    &Bs[(wc * 64 + nt * 16 + lr) * 64 + (((k2 * 4 + quad) ^ (lr & 7)) * 8)]);
            #pragma unroll
            for (int mt = 0; mt < 4; ++mt)
                #pragma unroll
                for (int nt = 0; nt < 4; ++nt)
                    acc[mt][nt] = __builtin_amdgcn_mfma_f32_16x16x32_bf16(af[mt], bf[nt], acc[mt][nt], 0, 0, 0);
        }
    }

    const int whichblk = n0 / C_DIM;   // 0=Q,1=K,2=V (uniform; 768 % 128 == 0)
    if (whichblk == 2) {
        // --- V epilogue: transpose through LDS, sigma-permuted 16B stores ---
        __syncthreads();
        #pragma unroll
        for (int nt = 0; nt < 4; ++nt) {
            int dp = wc * 64 + nt * 16 + lr;          // n within tile = 0..127
            float bj = bias[n0 + dp];
            #pragma unroll
            for (int mt = 0; mt < 4; ++mt) {
                int t0 = wr * 64 + mt * 16 + quad * 4;  // 4 consecutive t
                ushort4 u;
                u.x = f2b(acc[mt][nt][0] + bj);
                u.y = f2b(acc[mt][nt][1] + bj);
                u.z = f2b(acc[mt][nt][2] + bj);
                u.w = f2b(acc[mt][nt][3] + bj);
                int cs = (t0 >> 2) ^ ((dp & 15) << 1);   // even-XOR: keeps 8B groups
                *reinterpret_cast<ushort4*>(&SH[dp * 128 + cs * 4]) = u;
            }
        }
        __syncthreads();
        const int bb = m0 >> 12;
        const int t_base = m0 & 4095;
        const int h_base = (n0 - 2 * C_DIM) >> 6;
        #pragma unroll
        for (int i = 0; i < 8; ++i) {
            int idx = i * 256 + tid;
            int row = idx >> 4, cc = idx & 15;
            int tile = cc >> 3, cp = cc & 7;            // storage chunk in 64-tile
            // t-group (4t) index within the 128-t block: tile*16 + f*8 + quad
            int G0 = tile * 16 + ((cp >> 2) << 3) + (cp & 3);
            int swzr = (row & 15) << 1;
            uint2 lo = *reinterpret_cast<const uint2*>(&SH[row * 128 + ((G0 ^ swzr) * 4)]);
            uint2 hi = *reinterpret_cast<const uint2*>(&SH[row * 128 + (((G0 + 4) ^ swzr) * 4)]);
            uint4 val = {lo.x, lo.y, hi.x, hi.y};
            int head = h_base + (row >> 6);
            int d = row & 63;
            *reinterpret_cast<uint4*>(
                &Vt[((size_t)(bb * H_NUM + head) * D_HEAD + d) * T_SEQ +
                    t_base + tile * 64 + cp * 8]) = val;
        }
    } else {
        // --- Q/K epilogue: direct stores (16-lane 32B segments) ---
        const int head0 = ((n0 % C_DIM) + wc * 64) >> 6;
        #pragma unroll
        for (int nt = 0; nt < 4; ++nt) {
            int d = nt * 16 + lr;
            float bj = bias[n0 + wc * 64 + nt * 16 + lr];
            #pragma unroll
            for (int mt = 0; mt < 4; ++mt) {
                #pragma unroll
                for (int reg = 0; reg < 4; ++reg) {
                    int i = m0 + wr * 64 + mt * 16 + quad * 4 + reg;
                    int bb = i >> 12, t = i & 4095;
                    float val = acc[mt][nt][reg] + bj;
                    size_t base = (size_t)(bb * H_NUM + head0) * T_SEQ + t;
                    if (whichblk == 0)
                        Q[base * D_HEAD + d] = f2b(val * 0.18033688011f);  // 0.125*log2(e)
                    else
                        K[base * D_HEAD + d] = f2b(val);
                }
            }
        }
    }
}

// ---------------------------------------------------------------------------
// Flash attention (causal). R12 core: R10 schedule (bh-lockstep L2 locality)
// + bf16 partials + s_setprio around MFMA clusters. Register-PV via
// sigma-permuted V; ones-MFMA l; max-free log2-domain softmax; balanced
// split-K (every block exactly 33 k-iters).
// ---------------------------------------------------------------------------
__global__ __launch_bounds__(256, 3) void flash_attn(
    const unsigned short* __restrict__ Q, const unsigned short* __restrict__ K,
    const unsigned short* __restrict__ Vt, unsigned short* __restrict__ Y,
    unsigned short* __restrict__ pO, float* __restrict__ pl)
{
    __shared__ unsigned short Ks[2][64 * 64];   // [buf][key][d] xor-swizzled
    __shared__ unsigned short Vs[2][64 * 64];   // [buf][d][sigma-key] xor-swizzled
    const int tid  = threadIdx.x;
    const int lane = tid & 63;
    const int wv   = tid >> 6;
    const int quad = lane >> 4;
    const int lr   = lane & 15;
    const int srow = lane >> 3;
    const int dch  = (lane & 7) ^ srow;

    const int bid = blockIdx.x;
    const int ip  = bid / BHN;            // 0..31
    const int bh  = bid % BHN;            // bh-fast: same-bh blocks share an XCD (24%8==0)

    const unsigned short* Qb = Q  + (size_t)bh * T_SEQ * D_HEAD;
    const unsigned short* Kb = K  + (size_t)bh * T_SEQ * D_HEAD;
    const unsigned short* Vb = Vt + (size_t)bh * D_HEAD * T_SEQ;

    // --- job schedule: every block runs exactly 33 k-iters ---
    int njob, jqt[2], jk0[2], jk1[2], jpart[2];
    if (ip < 16) {
        njob = 2;
        jqt[0] = ip;      jk0[0] = 0; jk1[0] = 2 * ip + 2;  jpart[0] = 0;  // light: direct Y
        jqt[1] = 31 - ip; jk0[1] = 0; jk1[1] = 31 - 2 * ip; jpart[1] = 1;  // heavy head -> slot 0
    } else {
        njob = 1;
        jqt[0] = ip; jk0[0] = 2 * ip - 31; jk1[0] = 2 * ip + 2; jpart[0] = 2; // heavy tail -> slot 1
    }

    bf16x8 ones;
    #pragma unroll
    for (int i = 0; i < 8; ++i) ones[i] = (__bf16)1.0f;
    const f32x4 zf = {};

    const int bb = bh / H_NUM, hh = bh % H_NUM;

    int buf = 0;
    {   // prefetch first tile of job 0 into buf 0
        int kt = jk0[0];
        #pragma unroll
        for (int i = 0; i < 2; ++i) {
            int inst = wv * 2 + i;
            int r = inst * 8 + srow;
            load_lds16(Kb + (size_t)(kt * 64 + r) * D_HEAD + dch * 8, Ks[0] + inst * 512);
            load_lds16(Vb + (size_t)r * T_SEQ + kt * 64 + dch * 8, Vs[0] + inst * 512);
        }
    }

    for (int job = 0; job < njob; ++job) {
        const int qt = jqt[job];
        const int q0 = qt * 128;
        const int diag0 = 2 * qt;          // kt of half-0 diagonal
        const int lastk = 2 * qt + 1;      // kt of half-1 diagonal
        const int k0 = jk0[job], k1 = jk1[job];

        // Q B-frags (n = q = lr); Q pre-scaled by 0.125*log2e
        bf16x8 bQ[2][2];
        #pragma unroll
        for (int h = 0; h < 2; ++h)
            #pragma unroll
            for (int k2 = 0; k2 < 2; ++k2)
                bQ[h][k2] = *reinterpret_cast<const bf16x8*>(
                    &Qb[(size_t)(q0 + h * 64 + wv * 16 + lr) * D_HEAD + k2 * 32 + quad * 8]);

        f32x4 oacc[2][4] = {};       // [half][dt]: row=d, col=q(lr)
        f32x4 lacc[2] = {};          // [half]: every reg = full column sum (l)

        for (int kt = k0; kt < k1; ++kt) {
            __syncthreads();   // drains prefetch of this tile (issued one iter ago)

            // overlapped prefetch of the next tile in the flat schedule
            int nkt = (kt + 1 < k1) ? (kt + 1) : ((job + 1 < njob) ? jk0[job + 1] : -1);
            if (nkt >= 0) {
                #pragma unroll
                for (int i = 0; i < 2; ++i) {
                    int inst = wv * 2 + i;
                    int r = inst * 8 + srow;
                    load_lds16(Kb + (size_t)(nkt * 64 + r) * D_HEAD + dch * 8,
                               Ks[buf ^ 1] + inst * 512);
                    load_lds16(Vb + (size_t)r * T_SEQ + nkt * 64 + dch * 8,
                               Vs[buf ^ 1] + inst * 512);
                }
            }

            const bool doh0 = (kt <= diag0);

            // K A-frags once per tile, shared across both halves
            bf16x8 aK[4][2];
            #pragma unroll
            for (int mt = 0; mt < 4; ++mt)
                #pragma unroll
                for (int k2 = 0; k2 < 2; ++k2)
                    aK[mt][k2] = *reinterpret_cast<const bf16x8*>(
                        &Ks[buf][(mt * 16 + lr) * 64 + (((k2 * 4 + quad) ^ (lr & 7)) * 8)]);

            // S^T[key][q] for both halves (independent MFMA chains)
            f32x4 st0[4], st1[4];
            __builtin_amdgcn_s_setprio(1);
            #pragma unroll
            for (int mt = 0; mt < 4; ++mt) {
                st1[mt] = __builtin_amdgcn_mfma_f32_16x16x32_bf16(aK[mt][0], bQ[1][0], zf, 0, 0, 0);
                st1[mt] = __builtin_amdgcn_mfma_f32_16x16x32_bf16(aK[mt][1], bQ[1][1], st1[mt], 0, 0, 0);
            }
            if (doh0) {
                #pragma unroll
                for (int mt = 0; mt < 4; ++mt) {
                    st0[mt] = __builtin_amdgcn_mfma_f32_16x16x32_bf16(aK[mt][0], bQ[0][0], zf, 0, 0, 0);
                    st0[mt] = __builtin_amdgcn_mfma_f32_16x16x32_bf16(aK[mt][1], bQ[0][1], st0[mt], 0, 0, 0);
                }
            }
            __builtin_amdgcn_s_setprio(0);

            // V A-frags issued early (overlap ds latency with exp2 VALU)
            bf16x8 aV[4][2];
            #pragma unroll
            for (int dt = 0; dt < 4; ++dt)
                #pragma unroll
                for (int f = 0; f < 2; ++f)
                    aV[dt][f] = *reinterpret_cast<const bf16x8*>(
                        &Vs[buf][(dt * 16 + lr) * 64 + (((f * 4 + quad) ^ (lr & 7)) * 8)]);

            // causal masks (diagonal tiles only)
            if (kt == diag0) {
                int qg = q0 + wv * 16 + lr;
                #pragma unroll
                for (int mt = 0; mt < 4; ++mt)
                    #pragma unroll
                    for (int reg = 0; reg < 4; ++reg)
                        if (kt * 64 + mt * 16 + quad * 4 + reg > qg) st0[mt][reg] = -INFINITY;
            }
            if (kt == lastk) {
                int qg = q0 + 64 + wv * 16 + lr;
                #pragma unroll
                for (int mt = 0; mt < 4; ++mt)
                    #pragma unroll
                    for (int reg = 0; reg < 4; ++reg)
                        if (kt * 64 + mt * 16 + quad * 4 + reg > qg) st1[mt][reg] = -INFINITY;
            }

            // p = exp2(s); pack -> PV B-frags DIRECTLY in registers.
            bf16x8 bP1a, bP1b, bP0a, bP0b;
            {
                #pragma unroll
                for (int mt = 0; mt < 4; ++mt)
                    #pragma unroll
                    for (int reg = 0; reg < 4; ++reg)
                        st1[mt][reg] = __builtin_amdgcn_exp2f(st1[mt][reg]);
                u32x4v u;
                u[0] = pack_trunc(st1[0][0], st1[0][1]);
                u[1] = pack_trunc(st1[0][2], st1[0][3]);
                u[2] = pack_trunc(st1[1][0], st1[1][1]);
                u[3] = pack_trunc(st1[1][2], st1[1][3]);
                bP1a = __builtin_bit_cast(bf16x8, u);
                u[0] = pack_trunc(st1[2][0], st1[2][1]);
                u[1] = pack_trunc(st1[2][2], st1[2][3]);
                u[2] = pack_trunc(st1[3][0], st1[3][1]);
                u[3] = pack_trunc(st1[3][2], st1[3][3]);
                bP1b = __builtin_bit_cast(bf16x8, u);
            }
            if (doh0) {
                #pragma unroll
                for (int mt = 0; mt < 4; ++mt)
                    #pragma unroll
                    for (int reg = 0; reg < 4; ++reg)
                        st0[mt][reg] = __builtin_amdgcn_exp2f(st0[mt][reg]);
                u32x4v u;
                u[0] = pack_trunc(st0[0][0], st0[0][1]);
                u[1] = pack_trunc(st0[0][2], st0[0][3]);
                u[2] = pack_trunc(st0[1][0], st0[1][1]);
                u[3] = pack_trunc(st0[1][2], st0[1][3]);
                bP0a = __builtin_bit_cast(bf16x8, u);
                u[0] = pack_trunc(st0[2][0], st0[2][1]);
                u[1] = pack_trunc(st0[2][2], st0[2][3]);
                u[2] = pack_trunc(st0[3][0], st0[3][1]);
                u[3] = pack_trunc(st0[3][2], st0[3][3]);
                bP0b = __builtin_bit_cast(bf16x8, u);
            }

            // O^T += V^T P^T ; l += 1^T P (ones-MFMA column sums)
            __builtin_amdgcn_s_setprio(1);
            if (doh0) {
                #pragma unroll
                for (int dt = 0; dt < 4; ++dt) {
                    oacc[0][dt] = __builtin_amdgcn_mfma_f32_16x16x32_bf16(aV[dt][0], bP0a, oacc[0][dt], 0, 0, 0);
                    oacc[0][dt] = __builtin_amdgcn_mfma_f32_16x16x32_bf16(aV[dt][1], bP0b, oacc[0][dt], 0, 0, 0);
                }
                lacc[0] = __builtin_amdgcn_mfma_f32_16x16x32_bf16(ones, bP0a, lacc[0], 0, 0, 0);
                lacc[0] = __builtin_amdgcn_mfma_f32_16x16x32_bf16(ones, bP0b, lacc[0], 0, 0, 0);
            }
            {
                #pragma unroll
                for (int dt = 0; dt < 4; ++dt) {
                    oacc[1][dt] = __builtin_amdgcn_mfma_f32_16x16x32_bf16(aV[dt][0], bP1a, oacc[1][dt], 0, 0, 0);
                    oacc[1][dt] = __builtin_amdgcn_mfma_f32_16x16x32_bf16(aV[dt][1], bP1b, oacc[1][dt], 0, 0, 0);
                }
                lacc[1] = __builtin_amdgcn_mfma_f32_16x16x32_bf16(ones, bP1a, lacc[1], 0, 0, 0);
                lacc[1] = __builtin_amdgcn_mfma_f32_16x16x32_bf16(ones, bP1b, lacc[1], 0, 0, 0);
            }
            __builtin_amdgcn_s_setprio(0);

            buf ^= 1;
        }

        // ---- per-job epilogue ----
        if (jpart[job] == 0) {
            // direct: normalize + store bf16 Y
            #pragma unroll
            for (int h = 0; h < 2; ++h) {
                float inv = 1.f / lacc[h][0];
                int q = q0 + h * 64 + wv * 16 + lr;
                #pragma unroll
                for (int dt = 0; dt < 4; ++dt) {
                    ushort4 u;
                    u.x = f2b(oacc[h][dt][0] * inv);
                    u.y = f2b(oacc[h][dt][1] * inv);
                    u.z = f2b(oacc[h][dt][2] * inv);
                    u.w = f2b(oacc[h][dt][3] * inv);
                    *reinterpret_cast<ushort4*>(
                        &Y[(size_t)(bb * T_SEQ + q) * C_DIM + hh * 64 + dt * 16 + quad * 4]) = u;
                }
            }
        } else {
            // partial: unnormalized bf16 O + f32 l to workspace slot
            const int slot = jpart[job] - 1;            // 0 = head chunk, 1 = tail chunk
            const int iH = 31 - qt;                     // 0..15
            const size_t s = (size_t)slot * 384 + (size_t)bh * 16 + iH;
            unsigned short* po = pO + s * 8192;         // [128 q][64 d] bf16
            float* plp = pl + s * 128;
            #pragma unroll
            for (int h = 0; h < 2; ++h) {
                int q = h * 64 + wv * 16 + lr;
                if (quad == 0) plp[q] = lacc[h][0];
                #pragma unroll
                for (int dt = 0; dt < 4; ++dt) {
                    ushort4 u;
                    u.x = f2b(oacc[h][dt][0]);
                    u.y = f2b(oacc[h][dt][1]);
                    u.z = f2b(oacc[h][dt][2]);
                    u.w = f2b(oacc[h][dt][3]);
                    *reinterpret_cast<ushort4*>(&po[q * 64 + dt * 16 + quad * 4]) = u;
                }
            }
        }
    }
}

// ---------------------------------------------------------------------------
// combine: heavy tiles (qt 16..31): O = part0 + part1 (bf16 partials),
// normalize by l0+l1, write bf16 Y. 384 blocks x 256 threads (~25MB read).
// ---------------------------------------------------------------------------
__global__ __launch_bounds__(256) void combine(
    const unsigned short* __restrict__ pO, const float* __restrict__ pl,
    unsigned short* __restrict__ Y)
{
    const int s   = blockIdx.x;          // 0..383
    const int tid = threadIdx.x;
    const int bh  = s / 16, iH = s % 16;
    const int qt  = 31 - iH;
    const int bb  = bh / H_NUM, hh = bh % H_NUM;
    const int q0  = qt * 128;
    const unsigned short* a = pO + (size_t)s * 8192;
    const unsigned short* b = pO + (size_t)(384 + s) * 8192;
    const float* la = pl + (size_t)s * 128;
    const float* lb = pl + (size_t)(384 + s) * 128;
    #pragma unroll
    for (int j = 0; j < 8; ++j) {
        int idx = tid + j * 256;         // ushort4 index, 0..2047
        int f = idx * 4;
        int q = f >> 6, d0 = f & 63;
        ushort4 ua = *reinterpret_cast<const ushort4*>(&a[f]);
        ushort4 ub = *reinterpret_cast<const ushort4*>(&b[f]);
        float inv = 1.f / (la[q] + lb[q]);
        ushort4 u;
        u.x = f2b((b2f(ua.x) + b2f(ub.x)) * inv);
        u.y = f2b((b2f(ua.y) + b2f(ub.y)) * inv);
        u.z = f2b((b2f(ua.z) + b2f(ub.z)) * inv);
        u.w = f2b((b2f(ua.w) + b2f(ub.w)) * inv);
        *reinterpret_cast<ushort4*>(
            &Y[(size_t)(bb * T_SEQ + q0 + q) * C_DIM + hh * 64 + d0]) = u;
    }
}

// ---------------------------------------------------------------------------
// Output projection, R16: reverted to the R14 128x64-tile config (768 blocks
// = exactly 3/CU, ONE balanced round ~22us; R15's 128x128/384-block version
// was 1.5 blocks/CU ragged -> 2 rounds ~28us) + XCD swizzle (768 = 8 x 96).
// ---------------------------------------------------------------------------
__global__ __launch_bounds__(256) void out_gemm(
    const unsigned short* __restrict__ Y, const unsigned short* __restrict__ wt,
    const float* __restrict__ bias, float* __restrict__ out)
{
    __shared__ unsigned short As[128 * 64];
    __shared__ unsigned short Bs[64 * 64];
    const int tid  = threadIdx.x;
    const int bid  = blockIdx.y * 64 + blockIdx.x;
    const int swz  = (bid & 7) * 96 + (bid >> 3);    // XCD-contiguous (768 = 8*96)
    const int m0   = (swz & 63) * 128;
    const int n0   = (swz >> 6) * 64;
    const int lane = tid & 63;
    const int wv   = tid >> 6;
    const int wr   = wv >> 1, wc = wv & 1;   // wave tile: 64m x 32n
    const int quad = lane >> 4;
    const int lr   = lane & 15;
    const int srow = lane >> 3;
    const int dch  = (lane & 7) ^ srow;

    f32x4 acc[4][2] = {};

    for (int kk = 0; kk < C_DIM; kk += 64) {
        __syncthreads();
        #pragma unroll
        for (int i = 0; i < 4; ++i) {
            int inst = wv * 4 + i;
            int r = inst * 8 + srow;
            load_lds16(Y + (size_t)(m0 + r) * C_DIM + kk + dch * 8, As + inst * 512);
        }
        #pragma unroll
        for (int i = 0; i < 2; ++i) {
            int inst = wv * 2 + i;
            int r = inst * 8 + srow;
            load_lds16(wt + (size_t)(n0 + r) * C_DIM + kk + dch * 8, Bs + inst * 512);
        }
        __syncthreads();
        #pragma unroll
        for (int k2 = 0; k2 < 2; ++k2) {
            bf16x8 af[4], bf[2];
            #pragma unroll
            for (int mt = 0; mt < 4; ++mt)
                af[mt] = *reinterpret_cast<const bf16x8*>(
                    &As[(wr * 64 + mt * 16 + lr) * 64 + (((k2 * 4 + quad) ^ (lr & 7)) * 8)]);
            #pragma unroll
            for (int nt = 0; nt < 2; ++nt)
                bf[nt] = *reinterpret_cast<const bf16x8*>(
                    &Bs[(wc * 32 + nt * 16 + lr) * 64 + (((k2 * 4 + quad) ^ (lr & 7)) * 8)]);
            #pragma unroll
            for (int mt = 0; mt < 4; ++mt)
                #pragma unroll
                for (int nt = 0; nt < 2; ++nt)
                    acc[mt][nt] = __builtin_amdgcn_mfma_f32_16x16x32_bf16(af[mt], bf[nt], acc[mt][nt], 0, 0, 0);
        }
    }

    #pragma unroll
    for (int nt = 0; nt < 2; ++nt) {
        int j = n0 + wc * 32 + nt * 16 + lr;
        float bj = bias[j];
        #pragma unroll
        for (int mt = 0; mt < 4; ++mt)
            #pragma unroll
            for (int reg = 0; reg < 4; ++reg) {
                int i = m0 + wr * 64 + mt * 16 + quad * 4 + reg;
                out[(size_t)i * C_DIM + j] = acc[mt][nt][reg] + bj;
            }
    }
}

// ---------------------------------------------------------------------------
extern "C" void kernel_launch(void* const* d_in, const int* in_sizes, int n_in,
                              void* d_out, int out_size, void* d_ws, size_t ws_size,
                              hipStream_t stream) {
    const float* x     = (const float*)d_in[0];
    const float* qkv_w = (const float*)d_in[1];
    const float* qkv_b = (const float*)d_in[2];
    const float* out_w = (const float*)d_in[3];
    const float* out_b = (const float*)d_in[4];
    float* out = (float*)d_out;

    unsigned short* xb  = (unsigned short*)d_ws;            // [8192][768], reused as Y
    unsigned short* wtq = xb  + (size_t)8192 * 768;         // [2304][768]
    unsigned short* wto = wtq + (size_t)2304 * 768;         // [768][768]
    unsigned short* Qs  = wto + (size_t)768 * 768;
    unsigned short* Kg  = Qs  + (size_t)BHN * T_SEQ * D_HEAD;
    unsigned short* Vt  = Kg  + (size_t)BHN * T_SEQ * D_HEAD;
    unsigned short* pO  = Vt  + (size_t)BHN * T_SEQ * D_HEAD;   // bf16 [2][384][128][64]
    float*          pl  = (float*)(pO + (size_t)2 * 384 * 8192); // f32 [2][384][128]
    unsigned short* Y   = xb;   // alias: xb dead after qkv_gemm

    prep      <<<6720, 256, 0, stream>>>(x, qkv_w, out_w, xb, wtq, wto);
    qkv_gemm  <<<dim3(64, 18), 256, 0, stream>>>(xb, wtq, qkv_b, Qs, Kg, Vt);
    flash_attn<<<dim3(32 * BHN), 256, 0, stream>>>(Qs, Kg, Vt, Y, pO, pl);
    combine   <<<384, 256, 0, stream>>>(pO, pl, Y);
    out_gemm  <<<dim3(64, 12), 256, 0, stream>>>(Y, wto, out_b, out);
}

// Round 12
// 201.256 us; speedup vs baseline: 1.0744x; 1.0744x over previous
//
#include <hip/hip_runtime.h>
#include <hip/hip_bf16.h>

// Problem constants: B=2, T=4096, C=768, H=12, D=64
#define T_SEQ 4096
#define C_DIM 768
#define H_NUM 12
#define D_HEAD 64
#define N3    2304   // 3*C
#define BHN   24     // B*H

typedef __bf16 bf16x8 __attribute__((ext_vector_type(8)));
typedef float  f32x4  __attribute__((ext_vector_type(4)));
typedef unsigned int u32x4v __attribute__((ext_vector_type(4)));

// fp32 -> bf16 (round-to-nearest-even), raw bits
__device__ inline unsigned short f2b(float f) {
    unsigned int x = __float_as_uint(f);
    unsigned int r = (x + 0x7FFFu + ((x >> 16) & 1u)) >> 16;
    return (unsigned short)r;
}

__device__ inline float b2f(unsigned short u) {
    return __uint_as_float(((unsigned int)u) << 16);
}

// pack two f32 -> two bf16 (TRUNCATED) in one v_perm_b32: low half = lo
__device__ inline unsigned int pack_trunc(float lo, float hi) {
    return __builtin_amdgcn_perm(__float_as_uint(hi), __float_as_uint(lo), 0x07060302u);
}

// 16B-per-lane async global->LDS (dest = wave-uniform base + lane*16)
__device__ inline void load_lds16(const unsigned short* g, unsigned short* l) {
    __builtin_amdgcn_global_load_lds(
        (const __attribute__((address_space(1))) unsigned int*)(g),
        (__attribute__((address_space(3))) unsigned int*)(l),
        16, 0, 0);
}

// ---------------------------------------------------------------------------
// prep: fused [convert x -> bf16] + [transpose qkv_w] + [transpose out_w]
// ---------------------------------------------------------------------------
__device__ inline void transpose_tile(const float* __restrict__ in,
                                      unsigned short* __restrict__ out,
                                      unsigned short* Ts, int k0, int n0,
                                      int R, int Cc, int tid)
{
    #pragma unroll
    for (int it = 0; it < 4; ++it) {
        int idx = tid + it * 256;
        int r = idx >> 4, c4 = idx & 15;
        float4 v = *reinterpret_cast<const float4*>(&in[(size_t)(k0 + r) * Cc + n0 + c4 * 4]);
        Ts[(c4 * 4 + 0) * 72 + r] = f2b(v.x);
        Ts[(c4 * 4 + 1) * 72 + r] = f2b(v.y);
        Ts[(c4 * 4 + 2) * 72 + r] = f2b(v.z);
        Ts[(c4 * 4 + 3) * 72 + r] = f2b(v.w);
    }
    __syncthreads();
    #pragma unroll
    for (int it = 0; it < 2; ++it) {
        int idx = tid + it * 256;
        int row = idx >> 3, ch = idx & 7;
        *reinterpret_cast<uint4*>(&out[(size_t)(n0 + row) * R + k0 + ch * 8]) =
            *reinterpret_cast<const uint4*>(&Ts[row * 72 + ch * 8]);
    }
}

__global__ __launch_bounds__(256) void prep(
    const float* __restrict__ x, const float* __restrict__ qkv_w,
    const float* __restrict__ out_w,
    unsigned short* __restrict__ xb, unsigned short* __restrict__ wtq,
    unsigned short* __restrict__ wto)
{
    __shared__ unsigned short Ts[64 * 72];
    const int b = blockIdx.x, tid = threadIdx.x;
    if (b < 6144) {
        int idx = b * 256 + tid;
        float4 v = reinterpret_cast<const float4*>(x)[idx];
        ushort4 u;
        u.x = f2b(v.x); u.y = f2b(v.y); u.z = f2b(v.z); u.w = f2b(v.w);
        reinterpret_cast<ushort4*>(xb)[idx] = u;
    } else if (b < 6576) {
        int bb = b - 6144;
        transpose_tile(qkv_w, wtq, Ts, (bb % 12) * 64, (bb / 12) * 64, C_DIM, N3, tid);
    } else {
        int bb = b - 6576;
        transpose_tile(out_w, wto, Ts, (bb % 12) * 64, (bb / 12) * 64, C_DIM, C_DIM, tid);
    }
}

// ---------------------------------------------------------------------------
// QKV projection, R17: 128x96 tile. qkv's cost is makespan: 128x128 gave
// 1152 blocks on 768 co-resident slots = 2 rounds with the 2nd half-empty
// (wall 2*T128). N-tile 96 -> grid 64x24 = 1536 = EXACTLY 2 full rounds of
// 0.75x-cost blocks -> wall ~1.5*T128-equivalent. acc[4][3] = 48 AGPR +
// ~105 arch <= 170 -> 3 blocks/CU (launch_bounds(256,3)); MFMA:ds = 24:14
// per K-step. 768/96 = 8 so Q/K/V boundaries stay block-uniform; head/d
// computed per-element (48-wide wave spans head boundaries).
// V written sigma-PERMUTED along T within each 64-key tile:
//   sigma(k) = (k&32) + ((k>>2)&3)*8 + ((k>>4)&1)*4 + (k&3)
// so flash's PV B-operand is the QK output registers verbatim.
// ---------------------------------------------------------------------------
__global__ __launch_bounds__(256, 3) void qkv_gemm(
    const unsigned short* __restrict__ xb, const unsigned short* __restrict__ wt,
    const float* __restrict__ bias,
    unsigned short* __restrict__ Q, unsigned short* __restrict__ K,
    unsigned short* __restrict__ Vt)
{
    __shared__ unsigned short SH[128 * 64 + 96 * 64];  // As | Bs ; V epilogue reuses 96*128
    unsigned short* As = SH;                   // [128][64] xor-swizzled chunks
    unsigned short* Bs = SH + 128 * 64;        // [96][64]
    const int tid  = threadIdx.x;
    const int m0   = blockIdx.x * 128;
    const int n0   = blockIdx.y * 96;
    const int lane = tid & 63;
    const int wv   = tid >> 6;
    const int wr   = wv >> 1, wc = wv & 1;     // wave tile: 64m x 48n
    const int quad = lane >> 4;
    const int lr   = lane & 15;
    const int srow = lane >> 3;
    const int dch  = (lane & 7) ^ srow;

    f32x4 acc[4][3] = {};

    for (int kk = 0; kk < C_DIM; kk += 64) {
        __syncthreads();
        #pragma unroll
        for (int i = 0; i < 4; ++i) {
            int inst = wv * 4 + i;
            int r = inst * 8 + srow;
            load_lds16(xb + (size_t)(m0 + r) * C_DIM + kk + dch * 8, As + inst * 512);
        }
        #pragma unroll
        for (int i = 0; i < 3; ++i) {
            int inst = wv * 3 + i;                      // 12 insts cover 96 rows
            int r = inst * 8 + srow;
            load_lds16(wt + (size_t)(n0 + r) * C_DIM + kk + dch * 8, Bs + inst * 512);
        }
        __syncthreads();
        #pragma unroll
        for (int k2 = 0; k2 < 2; ++k2) {
            bf16x8 af[4], bf[3];
            #pragma unroll
            for (int mt = 0; mt < 4; ++mt)
                af[mt] = *reinterpret_cast<const bf16x8*>(
                    &As[(wr * 64 + mt * 16 + lr) * 64 + (((k2 * 4 + quad) ^ (lr & 7)) * 8)]);
            #pragma unroll
            for (int nt = 0; nt < 3; ++nt)
                bf[nt] = *reinterpret_cast<const bf16x8*>(
                    &Bs[(wc * 48 + nt * 16 + lr) * 64 + (((k2 * 4 + quad) ^ (lr & 7)) * 8)]);
            #pragma unroll
            for (int mt = 0; mt < 4; ++mt)
                #pragma unroll
                for (int nt = 0; nt < 3; ++nt)
                    acc[mt][nt] = __builtin_amdgcn_mfma_f32_16x16x32_bf16(af[mt], bf[nt], acc[mt][nt], 0, 0, 0);
        }
    }

    const int whichblk = n0 / C_DIM;   // 0=Q,1=K,2=V (uniform; 96 | 768)
    if (whichblk == 2) {
        // --- V epilogue: transpose through LDS (96 d-rows x 128 t),
        //     sigma-permuted 16B stores ---
        __syncthreads();
        #pragma unroll
        for (int nt = 0; nt < 3; ++nt) {
            int dp = wc * 48 + nt * 16 + lr;          // n within tile = 0..95
            float bj = bias[n0 + dp];
            #pragma unroll
            for (int mt = 0; mt < 4; ++mt) {
                int t0 = wr * 64 + mt * 16 + quad * 4;  // 4 consecutive t
                ushort4 u;
                u.x = f2b(acc[mt][nt][0] + bj);
                u.y = f2b(acc[mt][nt][1] + bj);
                u.z = f2b(acc[mt][nt][2] + bj);
                u.w = f2b(acc[mt][nt][3] + bj);
                int cs = (t0 >> 2) ^ ((dp & 15) << 1);   // even-XOR: keeps 8B groups
                *reinterpret_cast<ushort4*>(&SH[dp * 128 + cs * 4]) = u;
            }
        }
        __syncthreads();
        const int bb = m0 >> 12;
        const int t_base = m0 & 4095;
        const int c_base = n0 - 2 * C_DIM;            // 0..672, V-local column base
        #pragma unroll
        for (int i = 0; i < 6; ++i) {
            int idx = i * 256 + tid;                  // 0..1535
            int row = idx >> 4, cc = idx & 15;        // row = d-row within tile (0..95)
            int tile = cc >> 3, cp = cc & 7;          // storage chunk in 64-tile
            // t-group (4t) index within the 128-t block: tile*16 + f*8 + quad
            int G0 = tile * 16 + ((cp >> 2) << 3) + (cp & 3);
            int swzr = (row & 15) << 1;
            uint2 lo = *reinterpret_cast<const uint2*>(&SH[row * 128 + ((G0 ^ swzr) * 4)]);
            uint2 hi = *reinterpret_cast<const uint2*>(&SH[row * 128 + (((G0 + 4) ^ swzr) * 4)]);
            uint4 val = {lo.x, lo.y, hi.x, hi.y};
            int dcol = c_base + row;                  // 0..767
            int head = dcol >> 6;
            int d = dcol & 63;
            *reinterpret_cast<uint4*>(
                &Vt[((size_t)(bb * H_NUM + head) * D_HEAD + d) * T_SEQ +
                    t_base + tile * 64 + cp * 8]) = val;
        }
    } else {
        // --- Q/K epilogue: direct stores; head/d per-element (48n waves) ---
        #pragma unroll
        for (int nt = 0; nt < 3; ++nt) {
            int col = (n0 % C_DIM) + wc * 48 + nt * 16 + lr;   // 0..767
            int head = col >> 6;
            int d = col & 63;
            float bj = bias[n0 + wc * 48 + nt * 16 + lr];
            #pragma unroll
            for (int mt = 0; mt < 4; ++mt) {
                #pragma unroll
                for (int reg = 0; reg < 4; ++reg) {
                    int i = m0 + wr * 64 + mt * 16 + quad * 4 + reg;
                    int bb = i >> 12, t = i & 4095;
                    float val = acc[mt][nt][reg] + bj;
                    size_t base = (size_t)(bb * H_NUM + head) * T_SEQ + t;
                    if (whichblk == 0)
                        Q[base * D_HEAD + d] = f2b(val * 0.18033688011f);  // 0.125*log2(e)
                    else
                        K[base * D_HEAD + d] = f2b(val);
                }
            }
        }
    }
}

// ---------------------------------------------------------------------------
// Flash attention (causal). R12 core: R10 schedule (bh-lockstep L2 locality)
// + bf16 partials + s_setprio around MFMA clusters. Register-PV via
// sigma-permuted V; ones-MFMA l; max-free log2-domain softmax; balanced
// split-K (every block exactly 33 k-iters).
// ---------------------------------------------------------------------------
__global__ __launch_bounds__(256, 3) void flash_attn(
    const unsigned short* __restrict__ Q, const unsigned short* __restrict__ K,
    const unsigned short* __restrict__ Vt, unsigned short* __restrict__ Y,
    unsigned short* __restrict__ pO, float* __restrict__ pl)
{
    __shared__ unsigned short Ks[2][64 * 64];   // [buf][key][d] xor-swizzled
    __shared__ unsigned short Vs[2][64 * 64];   // [buf][d][sigma-key] xor-swizzled
    const int tid  = threadIdx.x;
    const int lane = tid & 63;
    const int wv   = tid >> 6;
    const int quad = lane >> 4;
    const int lr   = lane & 15;
    const int srow = lane >> 3;
    const int dch  = (lane & 7) ^ srow;

    const int bid = blockIdx.x;
    const int ip  = bid / BHN;            // 0..31
    const int bh  = bid % BHN;            // bh-fast: same-bh blocks share an XCD (24%8==0)

    const unsigned short* Qb = Q  + (size_t)bh * T_SEQ * D_HEAD;
    const unsigned short* Kb = K  + (size_t)bh * T_SEQ * D_HEAD;
    const unsigned short* Vb = Vt + (size_t)bh * D_HEAD * T_SEQ;

    // --- job schedule: every block runs exactly 33 k-iters ---
    int njob, jqt[2], jk0[2], jk1[2], jpart[2];
    if (ip < 16) {
        njob = 2;
        jqt[0] = ip;      jk0[0] = 0; jk1[0] = 2 * ip + 2;  jpart[0] = 0;  // light: direct Y
        jqt[1] = 31 - ip; jk0[1] = 0; jk1[1] = 31 - 2 * ip; jpart[1] = 1;  // heavy head -> slot 0
    } else {
        njob = 1;
        jqt[0] = ip; jk0[0] = 2 * ip - 31; jk1[0] = 2 * ip + 2; jpart[0] = 2; // heavy tail -> slot 1
    }

    bf16x8 ones;
    #pragma unroll
    for (int i = 0; i < 8; ++i) ones[i] = (__bf16)1.0f;
    const f32x4 zf = {};

    const int bb = bh / H_NUM, hh = bh % H_NUM;

    int buf = 0;
    {   // prefetch first tile of job 0 into buf 0
        int kt = jk0[0];
        #pragma unroll
        for (int i = 0; i < 2; ++i) {
            int inst = wv * 2 + i;
            int r = inst * 8 + srow;
            load_lds16(Kb + (size_t)(kt * 64 + r) * D_HEAD + dch * 8, Ks[0] + inst * 512);
            load_lds16(Vb + (size_t)r * T_SEQ + kt * 64 + dch * 8, Vs[0] + inst * 512);
        }
    }

    for (int job = 0; job < njob; ++job) {
        const int qt = jqt[job];
        const int q0 = qt * 128;
        const int diag0 = 2 * qt;          // kt of half-0 diagonal
        const int lastk = 2 * qt + 1;      // kt of half-1 diagonal
        const int k0 = jk0[job], k1 = jk1[job];

        // Q B-frags (n = q = lr); Q pre-scaled by 0.125*log2e
        bf16x8 bQ[2][2];
        #pragma unroll
        for (int h = 0; h < 2; ++h)
            #pragma unroll
            for (int k2 = 0; k2 < 2; ++k2)
                bQ[h][k2] = *reinterpret_cast<const bf16x8*>(
                    &Qb[(size_t)(q0 + h * 64 + wv * 16 + lr) * D_HEAD + k2 * 32 + quad * 8]);

        f32x4 oacc[2][4] = {};       // [half][dt]: row=d, col=q(lr)
        f32x4 lacc[2] = {};          // [half]: every reg = full column sum (l)

        for (int kt = k0; kt < k1; ++kt) {
            __syncthreads();   // drains prefetch of this tile (issued one iter ago)

            // overlapped prefetch of the next tile in the flat schedule
            int nkt = (kt + 1 < k1) ? (kt + 1) : ((job + 1 < njob) ? jk0[job + 1] : -1);
            if (nkt >= 0) {
                #pragma unroll
                for (int i = 0; i < 2; ++i) {
                    int inst = wv * 2 + i;
                    int r = inst * 8 + srow;
                    load_lds16(Kb + (size_t)(nkt * 64 + r) * D_HEAD + dch * 8,
                               Ks[buf ^ 1] + inst * 512);
                    load_lds16(Vb + (size_t)r * T_SEQ + nkt * 64 + dch * 8,
                               Vs[buf ^ 1] + inst * 512);
                }
            }

            const bool doh0 = (kt <= diag0);

            // K A-frags once per tile, shared across both halves
            bf16x8 aK[4][2];
            #pragma unroll
            for (int mt = 0; mt < 4; ++mt)
                #pragma unroll
                for (int k2 = 0; k2 < 2; ++k2)
                    aK[mt][k2] = *reinterpret_cast<const bf16x8*>(
                        &Ks[buf][(mt * 16 + lr) * 64 + (((k2 * 4 + quad) ^ (lr & 7)) * 8)]);

            // S^T[key][q] for both halves (independent MFMA chains)
            f32x4 st0[4], st1[4];
            __builtin_amdgcn_s_setprio(1);
            #pragma unroll
            for (int mt = 0; mt < 4; ++mt) {
                st1[mt] = __builtin_amdgcn_mfma_f32_16x16x32_bf16(aK[mt][0], bQ[1][0], zf, 0, 0, 0);
                st1[mt] = __builtin_amdgcn_mfma_f32_16x16x32_bf16(aK[mt][1], bQ[1][1], st1[mt], 0, 0, 0);
            }
            if (doh0) {
                #pragma unroll
                for (int mt = 0; mt < 4; ++mt) {
                    st0[mt] = __builtin_amdgcn_mfma_f32_16x16x32_bf16(aK[mt][0], bQ[0][0], zf, 0, 0, 0);
                    st0[mt] = __builtin_amdgcn_mfma_f32_16x16x32_bf16(aK[mt][1], bQ[0][1], st0[mt], 0, 0, 0);
                }
            }
            __builtin_amdgcn_s_setprio(0);

            // V A-frags issued early (overlap ds latency with exp2 VALU)
            bf16x8 aV[4][2];
            #pragma unroll
            for (int dt = 0; dt < 4; ++dt)
                #pragma unroll
                for (int f = 0; f < 2; ++f)
                    aV[dt][f] = *reinterpret_cast<const bf16x8*>(
                        &Vs[buf][(dt * 16 + lr) * 64 + (((f * 4 + quad) ^ (lr & 7)) * 8)]);

            // causal masks (diagonal tiles only)
            if (kt == diag0) {
                int qg = q0 + wv * 16 + lr;
                #pragma unroll
                for (int mt = 0; mt < 4; ++mt)
                    #pragma unroll
                    for (int reg = 0; reg < 4; ++reg)
                        if (kt * 64 + mt * 16 + quad * 4 + reg > qg) st0[mt][reg] = -INFINITY;
            }
            if (kt == lastk) {
                int qg = q0 + 64 + wv * 16 + lr;
                #pragma unroll
                for (int mt = 0; mt < 4; ++mt)
                    #pragma unroll
                    for (int reg = 0; reg < 4; ++reg)
                        if (kt * 64 + mt * 16 + quad * 4 + reg > qg) st1[mt][reg] = -INFINITY;
            }

            // p = exp2(s); pack -> PV B-frags DIRECTLY in registers.
            bf16x8 bP1a, bP1b, bP0a, bP0b;
            {
                #pragma unroll
                for (int mt = 0; mt < 4; ++mt)
                    #pragma unroll
                    for (int reg = 0; reg < 4; ++reg)
                        st1[mt][reg] = __builtin_amdgcn_exp2f(st1[mt][reg]);
                u32x4v u;
                u[0] = pack_trunc(st1[0][0], st1[0][1]);
                u[1] = pack_trunc(st1[0][2], st1[0][3]);
                u[2] = pack_trunc(st1[1][0], st1[1][1]);
                u[3] = pack_trunc(st1[1][2], st1[1][3]);
                bP1a = __builtin_bit_cast(bf16x8, u);
                u[0] = pack_trunc(st1[2][0], st1[2][1]);
                u[1] = pack_trunc(st1[2][2], st1[2][3]);
                u[2] = pack_trunc(st1[3][0], st1[3][1]);
                u[3] = pack_trunc(st1[3][2], st1[3][3]);
                bP1b = __builtin_bit_cast(bf16x8, u);
            }
            if (doh0) {
                #pragma unroll
                for (int mt = 0; mt < 4; ++mt)
                    #pragma unroll
                    for (int reg = 0; reg < 4; ++reg)
                        st0[mt][reg] = __builtin_amdgcn_exp2f(st0[mt][reg]);
                u32x4v u;
                u[0] = pack_trunc(st0[0][0], st0[0][1]);
                u[1] = pack_trunc(st0[0][2], st0[0][3]);
                u[2] = pack_trunc(st0[1][0], st0[1][1]);
                u[3] = pack_trunc(st0[1][2], st0[1][3]);
                bP0a = __builtin_bit_cast(bf16x8, u);
                u[0] = pack_trunc(st0[2][0], st0[2][1]);
                u[1] = pack_trunc(st0[2][2], st0[2][3]);
                u[2] = pack_trunc(st0[3][0], st0[3][1]);
                u[3] = pack_trunc(st0[3][2], st0[3][3]);
                bP0b = __builtin_bit_cast(bf16x8, u);
            }

            // O^T += V^T P^T ; l += 1^T P (ones-MFMA column sums)
            __builtin_amdgcn_s_setprio(1);
            if (doh0) {
                #pragma unroll
                for (int dt = 0; dt < 4; ++dt) {
                    oacc[0][dt] = __builtin_amdgcn_mfma_f32_16x16x32_bf16(aV[dt][0], bP0a, oacc[0][dt], 0, 0, 0);
                    oacc[0][dt] = __builtin_amdgcn_mfma_f32_16x16x32_bf16(aV[dt][1], bP0b, oacc[0][dt], 0, 0, 0);
                }
                lacc[0] = __builtin_amdgcn_mfma_f32_16x16x32_bf16(ones, bP0a, lacc[0], 0, 0, 0);
                lacc[0] = __builtin_amdgcn_mfma_f32_16x16x32_bf16(ones, bP0b, lacc[0], 0, 0, 0);
            }
            {
                #pragma unroll
                for (int dt = 0; dt < 4; ++dt) {
                    oacc[1][dt] = __builtin_amdgcn_mfma_f32_16x16x32_bf16(aV[dt][0], bP1a, oacc[1][dt], 0, 0, 0);
                    oacc[1][dt] = __builtin_amdgcn_mfma_f32_16x16x32_bf16(aV[dt][1], bP1b, oacc[1][dt], 0, 0, 0);
                }
                lacc[1] = __builtin_amdgcn_mfma_f32_16x16x32_bf16(ones, bP1a, lacc[1], 0, 0, 0);
                lacc[1] = __builtin_amdgcn_mfma_f32_16x16x32_bf16(ones, bP1b, lacc[1], 0, 0, 0);
            }
            __builtin_amdgcn_s_setprio(0);

            buf ^= 1;
        }

        // ---- per-job epilogue ----
        if (jpart[job] == 0) {
            // direct: normalize + store bf16 Y
            #pragma unroll
            for (int h = 0; h < 2; ++h) {
                float inv = 1.f / lacc[h][0];
                int q = q0 + h * 64 + wv * 16 + lr;
                #pragma unroll
                for (int dt = 0; dt < 4; ++dt) {
                    ushort4 u;
                    u.x = f2b(oacc[h][dt][0] * inv);
                    u.y = f2b(oacc[h][dt][1] * inv);
                    u.z = f2b(oacc[h][dt][2] * inv);
                    u.w = f2b(oacc[h][dt][3] * inv);
                    *reinterpret_cast<ushort4*>(
                        &Y[(size_t)(bb * T_SEQ + q) * C_DIM + hh * 64 + dt * 16 + quad * 4]) = u;
                }
            }
        } else {
            // partial: unnormalized bf16 O + f32 l to workspace slot
            const int slot = jpart[job] - 1;            // 0 = head chunk, 1 = tail chunk
            const int iH = 31 - qt;                     // 0..15
            const size_t s = (size_t)slot * 384 + (size_t)bh * 16 + iH;
            unsigned short* po = pO + s * 8192;         // [128 q][64 d] bf16
            float* plp = pl + s * 128;
            #pragma unroll
            for (int h = 0; h < 2; ++h) {
                int q = h * 64 + wv * 16 + lr;
                if (quad == 0) plp[q] = lacc[h][0];
                #pragma unroll
                for (int dt = 0; dt < 4; ++dt) {
                    ushort4 u;
                    u.x = f2b(oacc[h][dt][0]);
                    u.y = f2b(oacc[h][dt][1]);
                    u.z = f2b(oacc[h][dt][2]);
                    u.w = f2b(oacc[h][dt][3]);
                    *reinterpret_cast<ushort4*>(&po[q * 64 + dt * 16 + quad * 4]) = u;
                }
            }
        }
    }
}

// ---------------------------------------------------------------------------
// combine: heavy tiles (qt 16..31): O = part0 + part1 (bf16 partials),
// normalize by l0+l1, write bf16 Y. 384 blocks x 256 threads (~25MB read).
// ---------------------------------------------------------------------------
__global__ __launch_bounds__(256) void combine(
    const unsigned short* __restrict__ pO, const float* __restrict__ pl,
    unsigned short* __restrict__ Y)
{
    const int s   = blockIdx.x;          // 0..383
    const int tid = threadIdx.x;
    const int bh  = s / 16, iH = s % 16;
    const int qt  = 31 - iH;
    const int bb  = bh / H_NUM, hh = bh % H_NUM;
    const int q0  = qt * 128;
    const unsigned short* a = pO + (size_t)s * 8192;
    const unsigned short* b = pO + (size_t)(384 + s) * 8192;
    const float* la = pl + (size_t)s * 128;
    const float* lb = pl + (size_t)(384 + s) * 128;
    #pragma unroll
    for (int j = 0; j < 8; ++j) {
        int idx = tid + j * 256;         // ushort4 index, 0..2047
        int f = idx * 4;
        int q = f >> 6, d0 = f & 63;
        ushort4 ua = *reinterpret_cast<const ushort4*>(&a[f]);
        ushort4 ub = *reinterpret_cast<const ushort4*>(&b[f]);
        float inv = 1.f / (la[q] + lb[q]);
        ushort4 u;
        u.x = f2b((b2f(ua.x) + b2f(ub.x)) * inv);
        u.y = f2b((b2f(ua.y) + b2f(ub.y)) * inv);
        u.z = f2b((b2f(ua.z) + b2f(ub.z)) * inv);
        u.w = f2b((b2f(ua.w) + b2f(ub.w)) * inv);
        *reinterpret_cast<ushort4*>(
            &Y[(size_t)(bb * T_SEQ + q0 + q) * C_DIM + hh * 64 + d0]) = u;
    }
}

// ---------------------------------------------------------------------------
// Output projection: Y[8192,768](bf16) x wto[768,768]([n][k]) + bias -> fp32
// 128x64 tiles -> grid 768 blocks (exactly 3/CU, one balanced round).
// ---------------------------------------------------------------------------
__global__ __launch_bounds__(256) void out_gemm(
    const unsigned short* __restrict__ Y, const unsigned short* __restrict__ wt,
    const float* __restrict__ bias, float* __restrict__ out)
{
    __shared__ unsigned short As[128 * 64];
    __shared__ unsigned short Bs[64 * 64];
    const int tid  = threadIdx.x;
    const int m0   = blockIdx.x * 128;
    const int n0   = blockIdx.y * 64;
    const int lane = tid & 63;
    const int wv   = tid >> 6;
    const int wr   = wv >> 1, wc = wv & 1;   // wave tile: 64m x 32n
    const int quad = lane >> 4;
    const int lr   = lane & 15;
    const int srow = lane >> 3;
    const int dch  = (lane & 7) ^ srow;

    f32x4 acc[4][2] = {};

    for (int kk = 0; kk < C_DIM; kk += 64) {
        __syncthreads();
        #pragma unroll
        for (int i = 0; i < 4; ++i) {
            int inst = wv * 4 + i;
            int r = inst * 8 + srow;
            load_lds16(Y + (size_t)(m0 + r) * C_DIM + kk + dch * 8, As + inst * 512);
        }
        #pragma unroll
        for (int i = 0; i < 2; ++i) {
            int inst = wv * 2 + i;
            int r = inst * 8 + srow;
            load_lds16(wt + (size_t)(n0 + r) * C_DIM + kk + dch * 8, Bs + inst * 512);
        }
        __syncthreads();
        #pragma unroll
        for (int k2 = 0; k2 < 2; ++k2) {
            bf16x8 af[4], bf[2];
            #pragma unroll
            for (int mt = 0; mt < 4; ++mt)
                af[mt] = *reinterpret_cast<const bf16x8*>(
                    &As[(wr * 64 + mt * 16 + lr) * 64 + (((k2 * 4 + quad) ^ (lr & 7)) * 8)]);
            #pragma unroll
            for (int nt = 0; nt < 2; ++nt)
                bf[nt] = *reinterpret_cast<const bf16x8*>(
                    &Bs[(wc * 32 + nt * 16 + lr) * 64 + (((k2 * 4 + quad) ^ (lr & 7)) * 8)]);
            #pragma unroll
            for (int mt = 0; mt < 4; ++mt)
                #pragma unroll
                for (int nt = 0; nt < 2; ++nt)
                    acc[mt][nt] = __builtin_amdgcn_mfma_f32_16x16x32_bf16(af[mt], bf[nt], acc[mt][nt], 0, 0, 0);
        }
    }

    #pragma unroll
    for (int nt = 0; nt < 2; ++nt) {
        int j = n0 + wc * 32 + nt * 16 + lr;
        float bj = bias[j];
        #pragma unroll
        for (int mt = 0; mt < 4; ++mt)
            #pragma unroll
            for (int reg = 0; reg < 4; ++reg) {
                int i = m0 + wr * 64 + mt * 16 + quad * 4 + reg;
                out[(size_t)i * C_DIM + j] = acc[mt][nt][reg] + bj;
            }
    }
}

// ---------------------------------------------------------------------------
extern "C" void kernel_launch(void* const* d_in, const int* in_sizes, int n_in,
                              void* d_out, int out_size, void* d_ws, size_t ws_size,
                              hipStream_t stream) {
    const float* x     = (const float*)d_in[0];
    const float* qkv_w = (const float*)d_in[1];
    const float* qkv_b = (const float*)d_in[2];
    const float* out_w = (const float*)d_in[3];
    const float* out_b = (const float*)d_in[4];
    float* out = (float*)d_out;

    unsigned short* xb  = (unsigned short*)d_ws;            // [8192][768], reused as Y
    unsigned short* wtq = xb  + (size_t)8192 * 768;         // [2304][768]
    unsigned short* wto = wtq + (size_t)2304 * 768;         // [768][768]
    unsigned short* Qs  = wto + (size_t)768 * 768;
    unsigned short* Kg  = Qs  + (size_t)BHN * T_SEQ * D_HEAD;
    unsigned short* Vt  = Kg  + (size_t)BHN * T_SEQ * D_HEAD;
    unsigned short* pO  = Vt  + (size_t)BHN * T_SEQ * D_HEAD;   // bf16 [2][384][128][64]
    float*          pl  = (float*)(pO + (size_t)2 * 384 * 8192); // f32 [2][384][128]
    unsigned short* Y   = xb;   // alias: xb dead after qkv_gemm

    prep      <<<6720, 256, 0, stream>>>(x, qkv_w, out_w, xb, wtq, wto);
    qkv_gemm  <<<dim3(64, 24), 256, 0, stream>>>(xb, wtq, qkv_b, Qs, Kg, Vt);
    flash_attn<<<dim3(32 * BHN), 256, 0, stream>>>(Qs, Kg, Vt, Y, pO, pl);
    combine   <<<384, 256, 0, stream>>>(pO, pl, Y);
    out_gemm  <<<dim3(64, 12), 256, 0, stream>>>(Y, wto, out_b, out);
}